// Round 8
// baseline (271.122 us; speedup 1.0000x reference)
//
#include <hip/hip_runtime.h>
#include <cstdint>
#include <cstddef>

// B=2, N=4096, QDIM=768, H=8, D=64, INNER=512
// Pipeline: cvt x->bf16; LDS-tiled weight transposes; QKV gemm (bf16 MFMA,
// packed ushort4 epilogues) -> q (pre-scaled 0.125*log2e), k, vT;
// flash attention split over grid z (2 key-halves, 1024 blocks = 4/CU =
// 16 waves/CU; R7 post-mortem: 256-thr x 512 grid = 8 waves/CU killed the
// byte win) -> un-normalized bf16 O-partials + fp32 L-partials; elementwise
// merge (O0+O1)/(L0+L1) -> ob; out gemm + bias (C^T, float4 stores) -> fp32.

typedef __attribute__((ext_vector_type(8))) short short8;
typedef __attribute__((ext_vector_type(4))) float f32x4;

__device__ __forceinline__ unsigned short f2bf(float f) {
  // round-to-nearest-even bf16
  unsigned int u = __float_as_uint(f);
  u = (u + 0x7fffu + ((u >> 16) & 1u)) >> 16;
  return (unsigned short)u;
}

__device__ __forceinline__ float bf2f(unsigned short u) {
  return __uint_as_float((unsigned int)u << 16);
}

__device__ __forceinline__ float fast_exp2(float x) {
#if __has_builtin(__builtin_amdgcn_exp2f)
  return __builtin_amdgcn_exp2f(x);  // raw v_exp_f32
#else
  return __expf(x * 0.69314718055994531f);
#endif
}

__device__ __forceinline__ void gld16(const void* g, void* l) {
  // async global->LDS, 16B/lane; LDS dest = wave-uniform base + lane*16
  __builtin_amdgcn_global_load_lds(
      (__attribute__((address_space(1))) void*)const_cast<void*>(g),
      (__attribute__((address_space(3))) void*)l, 16, 0, 0);
}

// ---------------- prep kernels ----------------

__global__ __launch_bounds__(256) void cvt_x_k(const float* __restrict__ x,
                                               unsigned short* __restrict__ xb) {
  const size_t i = ((size_t)blockIdx.x * 256 + threadIdx.x) * 4;  // 6291456 elems
  const float4 v = *(const float4*)(x + i);
  ushort4 u;
  u.x = f2bf(v.x); u.y = f2bf(v.y); u.z = f2bf(v.z); u.w = f2bf(v.w);
  *(ushort4*)(xb + i) = u;
}

// One LDS-tiled transpose for all 4 weight matrices. fp32 [R][C] -> bf16 [C][R].
__global__ __launch_bounds__(256) void transpose_w_k(
    const float* __restrict__ Wq, const float* __restrict__ Wk,
    const float* __restrict__ Wv, const float* __restrict__ Wout,
    unsigned short* __restrict__ Wt,   // [3][512][768]
    unsigned short* __restrict__ WoT)  // [768][512]
{
  __shared__ float t[32][33];  // +1 pad: conflict-free transpose
  const int z = blockIdx.z;    // 0..2: Wq/Wk/Wv (768x512); 3: Wout (512x768)
  const float* src = (z == 0) ? Wq : (z == 1) ? Wk : (z == 2) ? Wv : Wout;
  const int R = (z < 3) ? 768 : 512, C = (z < 3) ? 512 : 768;
  unsigned short* dst = (z < 3) ? (Wt + (size_t)z * 393216) : WoT;
  const int tx = threadIdx.x & 31, ty = threadIdx.x >> 5;  // 32 x 8
  const int c0 = blockIdx.x * 32, r0 = blockIdx.y * 32;
  if (c0 >= C || r0 >= R) return;
#pragma unroll
  for (int k = 0; k < 4; ++k)
    t[ty + 8 * k][tx] = src[(size_t)(r0 + ty + 8 * k) * C + c0 + tx];
  __syncthreads();
#pragma unroll
  for (int k = 0; k < 4; ++k)
    dst[(size_t)(c0 + ty + 8 * k) * R + r0 + tx] = f2bf(t[tx][ty + 8 * k]);
}

// ---------------- QKV projection GEMM ----------------
// C[8192][512] = xb[8192][768] @ Wt[z]^T ; packed-store epilogues (R7 win):
// z=0,1 (q/k [bh][nseq][d]): SWAPPED mfma -> C^T, 4 r-values = 4 consecutive
//   d -> one ushort4 store.  z=2 (v^T [bh][d][nseq]): NORMAL mfma, 4 r-values
//   = 4 consecutive nseq -> one ushort4 store.
// Q pre-scaled by 0.125*log2(e) so attention can use exp2 directly.

__global__ __launch_bounds__(256) void gemm_qkv_k(
    const unsigned short* __restrict__ A,    // xb [8192][768]
    const unsigned short* __restrict__ Wt,   // [3][512][768]
    unsigned short* __restrict__ qb, unsigned short* __restrict__ kb,
    unsigned short* __restrict__ vtb) {
  __shared__ __align__(16) short Al[4096];  // [128][32]
  __shared__ __align__(16) short Bl[4096];  // [128][32]
  const int tid = threadIdx.x;
  const int w = tid >> 6, lane = tid & 63, quad = lane >> 4, l15 = lane & 15;
  const int wy = w >> 1, wx = w & 1;
  const int m0 = blockIdx.x * 128, n0 = blockIdx.y * 128;
  const int z = blockIdx.z;
  const unsigned short* Bt = Wt + (size_t)z * (512 * 768);

  f32x4 acc[4][4];
#pragma unroll
  for (int i = 0; i < 4; ++i)
#pragma unroll
    for (int j = 0; j < 4; ++j) acc[i][j] = (f32x4){0.f, 0.f, 0.f, 0.f};

  for (int k0 = 0; k0 < 768; k0 += 32) {
    __syncthreads();
#pragma unroll
    for (int s = 0; s < 2; ++s) {
      const int t = s * 256 + tid;
      gld16(A + (size_t)(m0 + (t >> 2)) * 768 + k0 + (t & 3) * 8,
            Al + s * 2048 + w * 512);
      gld16(Bt + (size_t)(n0 + (t >> 2)) * 768 + k0 + (t & 3) * 8,
            Bl + s * 2048 + w * 512);
    }
    __syncthreads();
    short8 af[4], bf[4];
#pragma unroll
    for (int i = 0; i < 4; ++i) {
      af[i] = *(const short8*)(Al + (wy * 64 + i * 16 + l15) * 32 + quad * 8);
      bf[i] = *(const short8*)(Bl + (wx * 64 + i * 16 + l15) * 32 + quad * 8);
    }
    if (z == 2) {
#pragma unroll
      for (int i = 0; i < 4; ++i)
#pragma unroll
        for (int j = 0; j < 4; ++j)
          acc[i][j] = __builtin_amdgcn_mfma_f32_16x16x32_bf16(af[i], bf[j], acc[i][j], 0, 0, 0);
    } else {
#pragma unroll
      for (int i = 0; i < 4; ++i)
#pragma unroll
        for (int j = 0; j < 4; ++j)
          acc[i][j] = __builtin_amdgcn_mfma_f32_16x16x32_bf16(bf[i], af[j], acc[i][j], 0, 0, 0);
    }
  }

  if (z == 2) {
#pragma unroll
    for (int i = 0; i < 4; ++i) {
#pragma unroll
      for (int j = 0; j < 4; ++j) {
        const int m0r = m0 + wy * 64 + i * 16 + quad * 4;  // nseq, r=0
        const int n = n0 + wx * 64 + j * 16 + l15;         // inner dim
        const int b = m0r >> 12, nseq0 = m0r & 4095;
        const int h = n >> 6, d = n & 63;
        ushort4 u;
        u.x = f2bf(acc[i][j][0]); u.y = f2bf(acc[i][j][1]);
        u.z = f2bf(acc[i][j][2]); u.w = f2bf(acc[i][j][3]);
        *(ushort4*)(vtb + (size_t)((b * 8 + h) * 64 + d) * 4096 + nseq0) = u;
      }
    }
  } else {
    const float qs = 0.18033688011112042f;  // 0.125*log2(e), z==0 only
#pragma unroll
    for (int i = 0; i < 4; ++i) {
#pragma unroll
      for (int j = 0; j < 4; ++j) {
        const int n0r = n0 + wx * 64 + i * 16 + quad * 4;  // inner dim, r=0
        const int m = m0 + wy * 64 + j * 16 + l15;         // nseq
        const int b = m >> 12, nseq = m & 4095;
        const int h = n0r >> 6, d0 = n0r & 63;
        ushort4 u;
        if (z == 0) {
          u.x = f2bf(acc[i][j][0] * qs); u.y = f2bf(acc[i][j][1] * qs);
          u.z = f2bf(acc[i][j][2] * qs); u.w = f2bf(acc[i][j][3] * qs);
          *(ushort4*)(qb + (size_t)((b * 8 + h) * 4096 + nseq) * 64 + d0) = u;
        } else {
          u.x = f2bf(acc[i][j][0]); u.y = f2bf(acc[i][j][1]);
          u.z = f2bf(acc[i][j][2]); u.w = f2bf(acc[i][j][3]);
          *(ushort4*)(kb + (size_t)((b * 8 + h) * 4096 + nseq) * 64 + d0) = u;
        }
      }
    }
  }
}

// ---------------- flash attention (partial, grid-z key split) ----------------
// grid (32, 16, 2): 128 q-rows x (b,h) x key-half -> 1024 blocks = 4/CU =
// 16 waves/CU. Block: 256 thr = 2 key-subgroups x 2 waves, 64 q/wave.
// j-tile = 32 keys so LDS fits 4 blocks: Kl 8 + Vl 8 + Pl 16 = 32 KB
// (merge scratch 33.8 KB is the block max). Static-max softmax -> block
// writes UN-NORMALIZED O-partial (bf16, RNE) + L-partial (fp32); merge_o_k
// finishes (O0+O1)/(L0+L1). S^T = mfma(K,Q) with b64-packed P round-trip.

__global__ __launch_bounds__(256) void attn_k(
    const unsigned short* __restrict__ qb,   // [16][4096][64], pre-scaled
    const unsigned short* __restrict__ kb,   // [16][4096][64]
    const unsigned short* __restrict__ vtb,  // [16][64][4096]
    unsigned short* __restrict__ op0,        // z=0 O-partial [8192][512] bf16
    unsigned short* __restrict__ op1,        // z=1 O-partial [8192][512] bf16
    float* __restrict__ lp) {                // L-partials [2][16][4096] fp32
  __shared__ __align__(16) char smem[33792];
  short* Kl = (short*)smem;            // [2g][2c][32 k][32 d] 8 KB
  short* Vl = (short*)(smem + 8192);   // [2g][64 d][32 k]     8 KB
  short* Pl = (short*)(smem + 16384);  // [4w][64 q][32 k]    16 KB

  const int tid = threadIdx.x;
  const int w = tid >> 6, lane = tid & 63, quad = lane >> 4, l15 = lane & 15;
  const int g = w >> 1, wq = w & 1;    // key-subgroup, wave-in-group
  const int z = blockIdx.z;
  const int bh = blockIdx.y;
  const int q0 = blockIdx.x * 128;
  const unsigned short* qbase = qb + (size_t)bh * 4096 * 64;
  const unsigned short* kbase = kb + (size_t)bh * 4096 * 64;
  const unsigned short* vbase = vtb + (size_t)bh * 64 * 4096;
  short* pw = Pl + w * 2048;
  short* KlG = Kl + g * 2048;
  short* VlG = Vl + g * 2048;
  const int jbase = z * 2048 + g * 1024;
  const int e4 = l15 & 3;              // P-buffer swizzle key (64B rows)

  // Q fragments live in registers all kernel (B-operand: n=l15, k=quad*8+j)
  short8 qf[4][2];
#pragma unroll
  for (int qh = 0; qh < 4; ++qh) {
    const int qrow = q0 + wq * 64 + qh * 16 + l15;
    qf[qh][0] = *(const short8*)(qbase + (size_t)qrow * 64 + quad * 8);
    qf[qh][1] = *(const short8*)(qbase + (size_t)qrow * 64 + 32 + quad * 8);
  }

  const short one_bf = (short)0x3F80;
  const short8 vones = {one_bf, one_bf, one_bf, one_bf,
                        one_bf, one_bf, one_bf, one_bf};

  f32x4 Oacc[4][4];
#pragma unroll
  for (int qh = 0; qh < 4; ++qh)
#pragma unroll
    for (int nf = 0; nf < 4; ++nf) Oacc[qh][nf] = (f32x4){0.f, 0.f, 0.f, 0.f};
  f32x4 Lacc[4];
#pragma unroll
  for (int qh = 0; qh < 4; ++qh) Lacc[qh] = (f32x4){0.f, 0.f, 0.f, 0.f};

  for (int j0 = 0; j0 < 1024; j0 += 32) {
    const int jj = jbase + j0;
    __syncthreads();
    // stage K (32 keys x 64 d, 2 d-chunks) + V^T (64 d x 32 keys): 4 gld16/wave
#pragma unroll
    for (int c = 0; c < 2; ++c)
      gld16(kbase + (size_t)(jj + wq * 16 + (lane >> 2)) * 64 + c * 32 + (lane & 3) * 8,
            KlG + (c * 32 + wq * 16) * 32);
#pragma unroll
    for (int h16 = 0; h16 < 2; ++h16)
      gld16(vbase + (size_t)(wq * 32 + h16 * 16 + (lane >> 2)) * 4096 + jj + (lane & 3) * 8,
            VlG + (wq * 32 + h16 * 16) * 32);
    __syncthreads();

    // S^T = mfma(K, Q): lane (quad,l15) holds keys kt*16+quad*4+r, q=l15.
    // exp2, pack pairs, one b64 store per (kt,qh) into P[q][32k] row-major,
    // XOR-swizzled on 16B blocks by l15&3 (row stride 64B).
#pragma unroll
    for (int kt = 0; kt < 2; ++kt) {
      const short8 ka0 = *(const short8*)(KlG + (0 * 32 + kt * 16 + l15) * 32 + quad * 8);
      const short8 ka1 = *(const short8*)(KlG + (1 * 32 + kt * 16 + l15) * 32 + quad * 8);
#pragma unroll
      for (int qh = 0; qh < 4; ++qh) {
        f32x4 st = (f32x4){0.f, 0.f, 0.f, 0.f};
        st = __builtin_amdgcn_mfma_f32_16x16x32_bf16(ka0, qf[qh][0], st, 0, 0, 0);
        st = __builtin_amdgcn_mfma_f32_16x16x32_bf16(ka1, qf[qh][1], st, 0, 0, 0);
        const unsigned int u0 = __float_as_uint(fast_exp2(st[0]));
        const unsigned int u1 = __float_as_uint(fast_exp2(st[1]));
        const unsigned int u2 = __float_as_uint(fast_exp2(st[2]));
        const unsigned int u3 = __float_as_uint(fast_exp2(st[3]));
        uint2 pd;
        pd.x = (u1 & 0xFFFF0000u) | (u0 >> 16);  // keys +0 (lo), +1 (hi)
        pd.y = (u3 & 0xFFFF0000u) | (u2 >> 16);  // keys +2, +3
        *(uint2*)(pw + (qh * 16 + l15) * 32 +
                  (((2 * kt + (quad >> 1)) ^ e4) * 8 + (quad & 1) * 4)) = pd;
      }
    }

    asm volatile("s_waitcnt lgkmcnt(0)" ::: "memory");  // wave-local P visible

    // O += P V ; L += P @ ones. A = P rows (b128, swizzled), B^T = V^T rows.
    short8 pa[4];
#pragma unroll
    for (int qh = 0; qh < 4; ++qh)
      pa[qh] = *(const short8*)(pw + (qh * 16 + l15) * 32 + ((quad ^ e4) * 8));
#pragma unroll
    for (int nf = 0; nf < 4; ++nf) {
      const short8 vb = *(const short8*)(VlG + (nf * 16 + l15) * 32 + quad * 8);
#pragma unroll
      for (int qh = 0; qh < 4; ++qh)
        Oacc[qh][nf] = __builtin_amdgcn_mfma_f32_16x16x32_bf16(
            pa[qh], vb, Oacc[qh][nf], 0, 0, 0);
    }
#pragma unroll
    for (int qh = 0; qh < 4; ++qh)
      Lacc[qh] = __builtin_amdgcn_mfma_f32_16x16x32_bf16(pa[qh], vones, Lacc[qh], 0, 0, 0);
  }

  // ----- merge the two in-block subgroups (additive), write partials -----
  __syncthreads();                       // all compute done; smem reusable
  float* Ox = (float*)smem;              // [128][65] fp32 (pad)
  float* Lx = (float*)(smem + 33280);    // [128]
  if (g == 1) {
#pragma unroll
    for (int qh = 0; qh < 4; ++qh)
#pragma unroll
      for (int r = 0; r < 4; ++r) {
        const int rl = wq * 64 + qh * 16 + quad * 4 + r;
        Lx[rl] = Lacc[qh][r];  // 16 identical lane copies -> benign dup write
#pragma unroll
        for (int nf = 0; nf < 4; ++nf)
          Ox[rl * 65 + nf * 16 + l15] = Oacc[qh][nf][r];
      }
  }
  __syncthreads();
  if (g == 0) {
    unsigned short* op = (z == 0) ? op0 : op1;
    float* lz = lp + z * 65536 + bh * 4096;
    const int b = bh >> 3, h = bh & 7;
#pragma unroll
    for (int qh = 0; qh < 4; ++qh)
#pragma unroll
      for (int r = 0; r < 4; ++r) {
        const int rl = wq * 64 + qh * 16 + quad * 4 + r;
        const float lsum = Lacc[qh][r] + Lx[rl];
        if (l15 == 0) lz[q0 + rl] = lsum;
        const int row = q0 + rl;
#pragma unroll
        for (int nf = 0; nf < 4; ++nf)
          op[(size_t)(b * 4096 + row) * 512 + h * 64 + nf * 16 + l15] =
              f2bf(Oacc[qh][nf][r] + Ox[rl * 65 + nf * 16 + l15]);
      }
  }
}

// ---------------- partial merge: ob = (O0+O1)/(L0+L1) ----------------

__global__ __launch_bounds__(256) void merge_o_k(
    const unsigned short* __restrict__ op0, const unsigned short* __restrict__ op1,
    const float* __restrict__ lp, unsigned short* __restrict__ ob) {
  const size_t i = ((size_t)blockIdx.x * 256 + threadIdx.x) * 4;  // 4194304 elems
  const int seq = (int)(i >> 9);            // b*4096 + nseq
  const int h = ((int)i & 511) >> 6;
  const int lidx = ((seq >> 12) * 8 + h) * 4096 + (seq & 4095);
  const float inv = 1.0f / (lp[lidx] + lp[65536 + lidx]);
  const ushort4 p0 = *(const ushort4*)(op0 + i);
  const ushort4 p1 = *(const ushort4*)(op1 + i);
  ushort4 o;
  o.x = f2bf((bf2f(p0.x) + bf2f(p1.x)) * inv);
  o.y = f2bf((bf2f(p0.y) + bf2f(p1.y)) * inv);
  o.z = f2bf((bf2f(p0.z) + bf2f(p1.z)) * inv);
  o.w = f2bf((bf2f(p0.w) + bf2f(p1.w)) * inv);
  *(ushort4*)(ob + i) = o;
}

// ---------------- output projection GEMM ----------------
// 128x64 tiles, SWAPPED mfma (C^T) -> float4 stores (R7 win).

__global__ __launch_bounds__(256) void gemm_out_k(
    const unsigned short* __restrict__ A,    // o [8192][512]
    const unsigned short* __restrict__ Bt,   // WoT [768][512]
    const float* __restrict__ bias, float* __restrict__ out) {
  __shared__ __align__(16) short Al[4096];  // [128][32]
  __shared__ __align__(16) short Bl[2048];  // [64][32]
  const int tid = threadIdx.x;
  const int w = tid >> 6, lane = tid & 63, quad = lane >> 4, l15 = lane & 15;
  const int m0 = blockIdx.x * 128, n0 = blockIdx.y * 64;

  f32x4 acc[2][4];
#pragma unroll
  for (int i = 0; i < 2; ++i)
#pragma unroll
    for (int j = 0; j < 4; ++j) acc[i][j] = (f32x4){0.f, 0.f, 0.f, 0.f};

  for (int k0 = 0; k0 < 512; k0 += 32) {
    __syncthreads();
#pragma unroll
    for (int s = 0; s < 2; ++s) {
      const int t = s * 256 + tid;
      gld16(A + (size_t)(m0 + (t >> 2)) * 512 + k0 + (t & 3) * 8,
            Al + s * 2048 + w * 512);
    }
    gld16(Bt + (size_t)(n0 + (tid >> 2)) * 512 + k0 + (tid & 3) * 8,
          Bl + w * 512);
    __syncthreads();
    short8 af[2], bf[4];
#pragma unroll
    for (int i = 0; i < 2; ++i)
      af[i] = *(const short8*)(Al + (w * 32 + i * 16 + l15) * 32 + quad * 8);
#pragma unroll
    for (int j = 0; j < 4; ++j)
      bf[j] = *(const short8*)(Bl + (j * 16 + l15) * 32 + quad * 8);
#pragma unroll
    for (int i = 0; i < 2; ++i)
#pragma unroll
      for (int j = 0; j < 4; ++j)
        acc[i][j] = __builtin_amdgcn_mfma_f32_16x16x32_bf16(bf[j], af[i], acc[i][j], 0, 0, 0);
  }

#pragma unroll
  for (int i = 0; i < 2; ++i) {
#pragma unroll
    for (int j = 0; j < 4; ++j) {
      const int col0 = n0 + j * 16 + quad * 4;
      const int m = m0 + w * 32 + i * 16 + l15;
      const float4 b4 = *(const float4*)(bias + col0);
      float4 o;
      o.x = acc[i][j][0] + b4.x; o.y = acc[i][j][1] + b4.y;
      o.z = acc[i][j][2] + b4.z; o.w = acc[i][j][3] + b4.w;
      *(float4*)(out + (size_t)m * 768 + col0) = o;
    }
  }
}

// ---------------- launch ----------------

extern "C" void kernel_launch(void* const* d_in, const int* in_sizes, int n_in,
                              void* d_out, int out_size, void* d_ws, size_t ws_size,
                              hipStream_t stream) {
  const float* x    = (const float*)d_in[0];
  const float* Wq   = (const float*)d_in[1];
  const float* Wk   = (const float*)d_in[2];
  const float* Wv   = (const float*)d_in[3];
  const float* Wout = (const float*)d_in[4];
  const float* bout = (const float*)d_in[5];
  float* out = (float*)d_out;
  char* ws = (char*)d_ws;

  // ws layout (bytes), total 49,283,072
  unsigned short* xb  = (unsigned short*)(ws);              // 12,582,912
  unsigned short* Wt  = (unsigned short*)(ws + 12582912);   //  2,359,296
  unsigned short* WoT = (unsigned short*)(ws + 14942208);   //    786,432
  unsigned short* qb  = (unsigned short*)(ws + 15728640);   //  8,388,608
  unsigned short* kb  = (unsigned short*)(ws + 24117248);   //  8,388,608
  unsigned short* vtb = (unsigned short*)(ws + 32505856);   //  8,388,608
  unsigned short* ob  = (unsigned short*)(ws + 40894464);   //  8,388,608
  // regions freed after gemm_qkv, reused by attention partials:
  unsigned short* op1 = xb;                 // z=1 O-partial (8.39 MB <= 12.58)
  float*          lpart = (float*)Wt;       // L-partials (0.52 MB <= 2.36)
  unsigned short* op0 = ob;                 // z=0 O-partial (in-place w/ merge)

  cvt_x_k<<<6144, 256, 0, stream>>>(x, xb);
  transpose_w_k<<<dim3(24, 24, 4), 256, 0, stream>>>(Wq, Wk, Wv, Wout, Wt, WoT);
  gemm_qkv_k<<<dim3(64, 4, 3), 256, 0, stream>>>(xb, Wt, qb, kb, vtb);
  attn_k<<<dim3(32, 16, 2), 256, 0, stream>>>(qb, kb, vtb, op0, op1, lpart);
  merge_o_k<<<4096, 256, 0, stream>>>(op0, op1, lpart, ob);
  gemm_out_k<<<dim3(64, 12), 256, 0, stream>>>(ob, WoT, bout, out);
}